// Round 2
// baseline (8274.155 us; speedup 1.0000x reference)
//
#include <hip/hip_runtime.h>
#include <stdint.h>

// Dims (fixed by the reference)
#define SS 128   // tokens
#define DD 128   // embed
#define EE 4     // experts
#define HH 8     // heads
#define HDIM 16  // head dim
#define FF 512   // ffn dim
#define BB 512   // batch
#define KK 2     // routed slots
#define NTASK (BB*KK)
#define MAXNF 0.99999f  // 1 - 1e-5

typedef unsigned short u16;
typedef unsigned int u32;

__device__ __forceinline__ float bf2f(u16 h){ return __uint_as_float(((u32)h)<<16); }
__device__ __forceinline__ u16 f2bf(float f){
  u32 x = __float_as_uint(f);
  u32 r = x + 0x7FFFu + ((x>>16)&1u);   // RNE, finite values only
  return (u16)(r>>16);
}
__device__ __forceinline__ float bfl(u32 u){ return __uint_as_float(u<<16); }
__device__ __forceinline__ float bfh(u32 u){ return __uint_as_float(u & 0xFFFF0000u); }

__device__ __forceinline__ float wsum(float v){
  #pragma unroll
  for(int off=32; off>0; off>>=1) v += __shfl_xor(v, off, 64);
  return v;
}
__device__ __forceinline__ float wmax(float v){
  #pragma unroll
  for(int off=32; off>0; off>>=1) v = fmaxf(v, __shfl_xor(v, off, 64));
  return v;
}
__device__ __forceinline__ float artanhf_(float x){ return 0.5f*logf((1.f+x)/(1.f-x)); }

// ---- dtype-generic scalar load / store ----
template<typename T> __device__ __forceinline__ float ldv(const T* p){
  if constexpr (sizeof(T)==2) return bf2f(*(const u16*)p);
  else return *(const float*)p;
}
template<typename T> __device__ __forceinline__ void stv(T* p, float v){
  if constexpr (sizeof(T)==2) *(u16*)p = f2bf(v);
  else *(float*)p = v;
}
// row of 128 weights -> 128 fp32 VGPRs
template<typename T> __device__ __forceinline__ void loadrow(const T* p, float* w){
  if constexpr (sizeof(T)==2){
    const uint4* q=(const uint4*)p;
    #pragma unroll
    for(int r=0;r<16;++r){
      uint4 t=q[r];
      w[r*8+0]=bfl(t.x); w[r*8+1]=bfh(t.x);
      w[r*8+2]=bfl(t.y); w[r*8+3]=bfh(t.y);
      w[r*8+4]=bfl(t.z); w[r*8+5]=bfh(t.z);
      w[r*8+6]=bfl(t.w); w[r*8+7]=bfh(t.w);
    }
  } else {
    const float4* q=(const float4*)p;
    #pragma unroll
    for(int r=0;r<32;++r){ float4 t=q[r]; w[r*4]=t.x; w[r*4+1]=t.y; w[r*4+2]=t.z; w[r*4+3]=t.w; }
  }
}
__device__ __forceinline__ float dotrow(const float* __restrict__ w, const float* __restrict__ u){
  float a0=0.f,a1=0.f,a2=0.f,a3=0.f;
  #pragma unroll
  for(int i=0;i<128;i+=4){
    a0+=w[i]*u[i]; a1+=w[i+1]*u[i+1]; a2+=w[i+2]*u[i+2]; a3+=w[i+3]*u[i+3];
  }
  return (a0+a1)+(a2+a3);
}

// ---- wave-cooperative row ops: row length = NPL*64, lane holds elems lane + i*64 ----
template<int NPL> __device__ __forceinline__ float vnorm(const float* v){
  float s=0.f;
  #pragma unroll
  for(int i=0;i<NPL;++i) s += v[i]*v[i];
  s = wsum(s);
  return sqrtf(fmaxf(s, 1e-15f));
}
template<int NPL> __device__ __forceinline__ void f_logmap0(float* v){
  float n = vnorm<NPL>(v);
  float sc = artanhf_(fminf(n, MAXNF))/n;
  #pragma unroll
  for(int i=0;i<NPL;++i) v[i]*=sc;
}
template<int NPL> __device__ __forceinline__ void f_expmap0(float* v){
  float n = vnorm<NPL>(v);
  float sc = tanhf(n)/n;
  #pragma unroll
  for(int i=0;i<NPL;++i) v[i]*=sc;
}
template<int NPL> __device__ __forceinline__ void f_projx(float* v){
  float n = vnorm<NPL>(v);
  if(n > MAXNF){
    float sc = MAXNF/n;
    #pragma unroll
    for(int i=0;i<NPL;++i) v[i]*=sc;
  }
}
template<int NPL> __device__ __forceinline__ void f_mobius_add(float* x, const float* y){
  float xy=0.f, x2=0.f, y2=0.f;
  #pragma unroll
  for(int i=0;i<NPL;++i){ xy+=x[i]*y[i]; x2+=x[i]*x[i]; y2+=y[i]*y[i]; }
  xy=wsum(xy); x2=wsum(x2); y2=wsum(y2);
  float cx = 1.f + 2.f*xy + y2;
  float cy = 1.f - x2;
  float den = fmaxf(1.f + 2.f*xy + x2*y2, 1e-15f);
  float inv = 1.f/den;
  #pragma unroll
  for(int i=0;i<NPL;++i) x[i] = (cx*x[i] + cy*y[i])*inv;
}
template<int NPL> __device__ __forceinline__ void f_layernorm(float* v, const float* g, const float* b){
  const float invD = 1.f/(float)(NPL*64);
  float m=0.f;
  #pragma unroll
  for(int i=0;i<NPL;++i) m += v[i];
  m = wsum(m)*invD;
  float s2=0.f;
  #pragma unroll
  for(int i=0;i<NPL;++i){ v[i]-=m; s2 += v[i]*v[i]; }
  s2 = wsum(s2)*invD;
  float inv = 1.f/sqrtf(s2+1e-5f);
  #pragma unroll
  for(int i=0;i<NPL;++i) v[i] = g[i]*(v[i]*inv) + b[i];
}

// ---- prep: (a) detect wire dtype of float tensors by scanning features for
// bf16 inf/NaN bit patterns (bf16 wire has none; f32 wire mantissa low-halves
// hit them with p~2^-8); (b) normalize padding mask (u8/i32/bf16/f32) to f32 bias ----
__global__ void prep_kernel(const u16* __restrict__ feat16,
                            const unsigned char* __restrict__ mask,
                            float* __restrict__ mbias, int* __restrict__ flag){
  __shared__ int s_stats, s_max, s_nan;
  if(threadIdx.x==0){ s_stats=0; s_max=0; s_nan=0; }
  __syncthreads();
  int c=0;
  for(int i=threadIdx.x; i<131072; i+=blockDim.x){
    u16 v = feat16[i];
    if(((v>>7)&0xFFu)==0xFFu) c++;
  }
  if(c) atomicAdd(&s_nan, c);
  int lstats=0, lmax=0;
  for(int i=threadIdx.x; i<BB*SS; i+=blockDim.x){
    int v = mask[i];
    if(v){
      lmax = v>lmax ? v : lmax;
      if((i&3)==1) lstats|=1;   // nonzero at byte pos %4==1 : u8 or bf16
      if((i&3)!=0) lstats|=2;   // nonzero at byte pos %4!=0 : not i32
    }
  }
  if(lstats) atomicOr(&s_stats, lstats);
  atomicMax(&s_max, lmax);
  __syncthreads();
  if(threadIdx.x==0) *flag = (s_nan>0) ? 1 : 0;   // 1 = f32 wire, 0 = bf16 wire
  int mode; // 0=u8 bool, 1=int32, 2=bf16, 3=f32
  if(s_max<=1) mode = (s_stats&2) ? 0 : 1;
  else         mode = (s_stats&1) ? 2 : 3;
  for(int i=threadIdx.x; i<BB*SS; i+=blockDim.x){
    bool m2;
    if(mode==0)      m2 = mask[i]!=0;
    else if(mode==1) m2 = ((const int*)mask)[i]!=0;
    else if(mode==2) m2 = ((const u16*)mask)[i]!=0;
    else             m2 = ((((const u32*)mask)[i])<<1)!=0;
    mbias[i] = m2 ? -1e9f : 0.f;
  }
}

// zero the non-routed output slabs (gated on wire dtype)
template<typename T>
__global__ void zero_nr(const int* __restrict__ flag, const int* __restrict__ eidx, T* __restrict__ out){
  const int want = (sizeof(T)==4) ? 1 : 0;
  if(*flag != want) return;
  for(int slab=blockIdx.x; slab<BB*EE; slab+=gridDim.x){
    int b = slab>>2, e = slab&3;
    if(eidx[b*KK]==e || eidx[b*KK+1]==e) continue;
    T* p = out + (size_t)slab*(SS*DD);
    for(int i=threadIdx.x; i<SS*DD; i+=blockDim.x){
      if constexpr (sizeof(T)==2) p[i] = (T)0; else p[i] = 0.f;
    }
  }
}

template<typename T>
__global__ __launch_bounds__(256)
void moe_kernel(const int* __restrict__ flag,
                const T* __restrict__ feat, const int* __restrict__ eidx,
                const float* __restrict__ mbias,
                const T* __restrict__ ln1g, const T* __restrict__ ln1b,
                const T* __restrict__ ln2g, const T* __restrict__ ln2b,
                const T* __restrict__ wq, const T* __restrict__ bq,
                const T* __restrict__ wk, const T* __restrict__ bk_,
                const T* __restrict__ wv, const T* __restrict__ bv,
                const T* __restrict__ wo, const T* __restrict__ bo,
                const T* __restrict__ f1w, const T* __restrict__ f1b,
                const T* __restrict__ f2w, const T* __restrict__ f2b,
                T* __restrict__ out, float* __restrict__ ws, int ntask)
{
  const int want = (sizeof(T)==4) ? 1 : 0;
  if(*flag != want) return;

  __shared__ float U[SS*DD];                 // 64 KB: current per-token "u" vectors
  const int tid  = threadIdx.x;
  const int lane = tid & 63;
  const int wid  = tid >> 6;                 // 4 waves per block
  float* T0 = ws + (size_t)blockIdx.x * (4*SS*DD);
  float* T1 = T0 + SS*DD;
  float* T2 = T1 + SS*DD;
  float* T3 = T2 + SS*DD;

  for(int task = blockIdx.x; task < ntask; task += gridDim.x){
    __syncthreads();                          // protect U across tasks
    const int b = task >> 1;
    const int e = eidx[b*KK + (task & 1)];
    const T* X = feat + (size_t)task * (SS*DD);

    // ---- P1: u1 = logmap0(expmap0(LN1(logmap0(x))))  -> U
    for(int r=0;r<32;++r){
      int t = wid*32 + r;
      float v[2];
      v[0]=ldv(&X[t*DD+lane]); v[1]=ldv(&X[t*DD+lane+64]);
      f_logmap0<2>(v);
      float g[2], bb[2];
      g[0]=ldv(&ln1g[e*DD+lane]);  g[1]=ldv(&ln1g[e*DD+lane+64]);
      bb[0]=ldv(&ln1b[e*DD+lane]); bb[1]=ldv(&ln1b[e*DD+lane+64]);
      f_layernorm<2>(v,g,bb);
      f_expmap0<2>(v);
      f_logmap0<2>(v);
      U[t*DD+lane]=v[0]; U[t*DD+lane+64]=v[1];
    }
    __syncthreads();

    // ---- P2: q/k/v matvecs (W row cached in 128 VGPRs) -> T0/T1/T2
    {
      int j = tid & 127, tg = tid >> 7;
      for(int m=0;m<3;++m){
        const T* Wm = (m==0?wq : m==1?wk : wv) + (size_t)e*DD*DD + (size_t)j*DD;
        float* Ym = (m==0?T0 : m==1?T1 : T2);
        float w[128];
        loadrow(Wm, w);
        for(int tt=0;tt<64;++tt){
          int t = tg*64+tt;
          Ym[t*DD+j] = dotrow(w, &U[t*DD]);
        }
      }
    }
    __syncthreads();

    // ---- P2 post: q/k/v = logmap0(projx(mobius_add(expmap0(Wu), expmap0(bias))))
    for(int m=0;m<3;++m){
      const T* bias = (m==0?bq : m==1?bk_ : bv) + e*DD;
      float* Y = (m==0?T0 : m==1?T1 : T2);
      for(int r=0;r<32;++r){
        int t = wid*32+r;
        float v[2]; v[0]=Y[t*DD+lane]; v[1]=Y[t*DD+lane+64];
        f_expmap0<2>(v);
        float ebv[2]; ebv[0]=ldv(&bias[lane]); ebv[1]=ldv(&bias[lane+64]);
        f_expmap0<2>(ebv);
        f_mobius_add<2>(v, ebv);
        f_projx<2>(v);
        f_logmap0<2>(v);
        Y[t*DD+lane]=v[0]; Y[t*DD+lane+64]=v[1];
      }
    }
    __syncthreads();

    // ---- P3: attention per head; ctx overwrites q slice in T0
    {
      const float* mb = mbias + b*SS;
      for(int h=0; h<HH; ++h){
        for(int r=0;r<32;++r){
          int t = wid*32+r;
          float q16[16];
          #pragma unroll
          for(int i=0;i<16;++i) q16[i] = T0[t*DD + h*HDIM + i];
          int k0 = lane, k1 = lane+64;
          float s0=0.f, s1=0.f;
          #pragma unroll
          for(int i=0;i<16;++i){
            s0 += q16[i]*T1[k0*DD + h*HDIM + i];
            s1 += q16[i]*T1[k1*DD + h*HDIM + i];
          }
          s0 = s0*0.25f + mb[k0];
          s1 = s1*0.25f + mb[k1];
          float mx = wmax(fmaxf(s0,s1));
          float p0 = expf(s0-mx), p1 = expf(s1-mx);
          float dn = wsum(p0+p1);
          p0 /= dn; p1 /= dn;
          float part[16];
          #pragma unroll
          for(int i=0;i<16;++i)
            part[i] = p0*T2[k0*DD+h*HDIM+i] + p1*T2[k1*DD+h*HDIM+i];
          #pragma unroll
          for(int off=1; off<64; off<<=1){
            #pragma unroll
            for(int i=0;i<16;++i) part[i] += __shfl_xor(part[i], off, 64);
          }
          if(lane==0){
            #pragma unroll
            for(int i=0;i<16;++i) T0[t*DD + h*HDIM + i] = part[i];
          }
        }
      }
    }
    __syncthreads();

    // ---- P4a: u_o = logmap0(expmap0(ctx)) -> U
    for(int r=0;r<32;++r){
      int t=wid*32+r;
      float v[2]; v[0]=T0[t*DD+lane]; v[1]=T0[t*DD+lane+64];
      f_expmap0<2>(v);
      f_logmap0<2>(v);
      U[t*DD+lane]=v[0]; U[t*DD+lane+64]=v[1];
    }
    __syncthreads();

    // ---- P4b: Wo matvec -> T1
    {
      int j=tid&127, tg=tid>>7;
      float w[128];
      loadrow(wo + (size_t)e*DD*DD + (size_t)j*DD, w);
      for(int tt=0;tt<64;++tt){
        int t=tg*64+tt;
        T1[t*DD+j] = dotrow(w, &U[t*DD]);
      }
    }
    __syncthreads();

    // ---- P4c: attn-out chain, residual, LN2 chain -> x1 in T3, u2 in U
    for(int r=0;r<32;++r){
      int t=wid*32+r;
      float v[2]; v[0]=T1[t*DD+lane]; v[1]=T1[t*DD+lane+64];
      f_expmap0<2>(v);
      float ebv[2]; ebv[0]=ldv(&bo[e*DD+lane]); ebv[1]=ldv(&bo[e*DD+lane+64]);
      f_expmap0<2>(ebv);
      f_mobius_add<2>(v, ebv);
      f_projx<2>(v);              // man_linear's projx
      f_projx<2>(v);              // _expert's projx(_mha(...))
      float res[2]; res[0]=ldv(&X[t*DD+lane]); res[1]=ldv(&X[t*DD+lane+64]);
      f_mobius_add<2>(v, res);
      f_projx<2>(v);              // x1
      T3[t*DD+lane]=v[0]; T3[t*DD+lane+64]=v[1];
      f_logmap0<2>(v);
      float g2[2], b2[2];
      g2[0]=ldv(&ln2g[e*DD+lane]); g2[1]=ldv(&ln2g[e*DD+lane+64]);
      b2[0]=ldv(&ln2b[e*DD+lane]); b2[1]=ldv(&ln2b[e*DD+lane+64]);
      f_layernorm<2>(v,g2,b2);
      f_expmap0<2>(v);
      f_projx<2>(v);
      f_logmap0<2>(v);            // u2
      U[t*DD+lane]=v[0]; U[t*DD+lane+64]=v[1];
    }
    __syncthreads();

    // ---- P5: FFN, two token chunks of 64; HID = T0..T1 as [64][512]
    float* HID = T0;
    for(int tc=0; tc<2; ++tc){
      // fc1 matvec: thread owns output f, loops 64 tokens
      for(int pass=0;pass<2;++pass){
        int f = pass*256 + tid;
        float w[128];
        loadrow(f1w + (size_t)e*FF*DD + (size_t)f*DD, w);
        for(int tt=0;tt<64;++tt){
          HID[tt*FF+f] = dotrow(w, &U[(tc*64+tt)*DD]);
        }
      }
      __syncthreads();
      // fc1 post (row length 512, 8 elems/lane)
      for(int r=0;r<16;++r){
        int t = wid*16+r;
        float v[8];
        #pragma unroll
        for(int i=0;i<8;++i) v[i]=HID[t*FF+lane+64*i];
        f_expmap0<8>(v);
        float ebv[8];
        #pragma unroll
        for(int i=0;i<8;++i) ebv[i]=ldv(&f1b[e*FF+lane+64*i]);
        f_expmap0<8>(ebv);
        f_mobius_add<8>(v, ebv);
        f_projx<8>(v);            // man_linear projx
        f_logmap0<8>(v);
        #pragma unroll
        for(int i=0;i<8;++i) v[i]=fmaxf(v[i],0.f);
        f_expmap0<8>(v);          // mob_relu
        f_projx<8>(v);            // h = projx(...)
        f_logmap0<8>(v);          // u3 for fc2
        #pragma unroll
        for(int i=0;i<8;++i) HID[t*FF+lane+64*i]=v[i];
      }
      __syncthreads();
      // fc2 matvec (dot-512 in 4 chunks of 128, W chunk cached) -> T2
      {
        int j=tid&127, tg=tid>>7;
        for(int fc=0;fc<4;++fc){
          float w[128];
          loadrow(f2w + (size_t)e*DD*FF + (size_t)j*FF + fc*128, w);
          for(int tt=0;tt<32;++tt){
            int t=tg*32+tt;
            float acc = dotrow(w, HID + t*FF + fc*128);
            if(fc==0) T2[t*DD+j]=acc; else T2[t*DD+j]+=acc;
          }
        }
      }
      __syncthreads();
      // fc2 post + residual + output store
      for(int r=0;r<16;++r){
        int t=wid*16+r; int gt = tc*64+t;
        float v[2]; v[0]=T2[t*DD+lane]; v[1]=T2[t*DD+lane+64];
        f_expmap0<2>(v);
        float ebv[2]; ebv[0]=ldv(&f2b[e*DD+lane]); ebv[1]=ldv(&f2b[e*DD+lane+64]);
        f_expmap0<2>(ebv);
        f_mobius_add<2>(v, ebv);
        f_projx<2>(v);            // man_linear projx
        f_logmap0<2>(v);
        v[0]=fmaxf(v[0],0.f); v[1]=fmaxf(v[1],0.f);
        f_expmap0<2>(v);          // mob_relu (no projx here per reference)
        float x1v[2]; x1v[0]=T3[gt*DD+lane]; x1v[1]=T3[gt*DD+lane+64];
        f_mobius_add<2>(v, x1v);
        f_projx<2>(v);
        T* op = out + ((size_t)(b*EE+e)*SS + gt)*DD;
        stv(&op[lane],    v[0]);
        stv(&op[lane+64], v[1]);
      }
      __syncthreads();
    }
  }
}

extern "C" void kernel_launch(void* const* d_in, const int* in_sizes, int n_in,
                              void* d_out, int out_size, void* d_ws, size_t ws_size,
                              hipStream_t stream){
  const void* feat = d_in[0];
  const int* eidx = (const int*)d_in[1];
  const unsigned char* pmask = (const unsigned char*)d_in[2];
  float* ws = (float*)d_ws;

  // ws layout: [0..15] flag, [16 .. 16+BB*SS) mbias, then per-block fp32 tiles
  int* flag = (int*)ws;
  float* mbias = ws + 16;
  float* tiles = ws + 16 + BB*SS;
  const size_t blkF = 4*SS*DD;
  long avail = (long)(ws_size/sizeof(float)) - (16 + BB*SS);
  int G = (int)(avail / (long)blkF);
  if(G > NTASK) G = NTASK;
  if(G < 1) G = 1;

  prep_kernel<<<1,256,0,stream>>>((const u16*)feat, pmask, mbias, flag);
  zero_nr<u16>  <<<2048,256,0,stream>>>(flag, eidx, (u16*)d_out);
  zero_nr<float><<<2048,256,0,stream>>>(flag, eidx, (float*)d_out);

  #define ARGS(T_) flag, (const T_*)d_in[0], eidx, mbias, \
    (const T_*)d_in[3], (const T_*)d_in[4], (const T_*)d_in[5], (const T_*)d_in[6], \
    (const T_*)d_in[7], (const T_*)d_in[8], (const T_*)d_in[9], (const T_*)d_in[10], \
    (const T_*)d_in[11], (const T_*)d_in[12], (const T_*)d_in[13], (const T_*)d_in[14], \
    (const T_*)d_in[15], (const T_*)d_in[16], (const T_*)d_in[17], (const T_*)d_in[18], \
    (T_*)d_out, tiles, NTASK
  moe_kernel<u16>  <<<G,256,0,stream>>>(ARGS(u16));
  moe_kernel<float><<<G,256,0,stream>>>(ARGS(float));
  #undef ARGS
}